// Round 10
// baseline (156.175 us; speedup 1.0000x reference)
//
#include <hip/hip_runtime.h>
#include <hip/hip_bf16.h>

typedef __attribute__((ext_vector_type(4))) float f32x4;
typedef __attribute__((ext_vector_type(8))) short bf16x8;

constexpr int Bn  = 4;
constexpr int Ln  = 1024;
constexpr int Dn  = 1024;
constexpr int Hn  = 16;
constexpr int HDn = 64;

static __device__ __forceinline__ unsigned short bf16r(float f) {
    union { float f; unsigned int u; } x;
    x.f = f;
    unsigned int r = x.u + 0x7fffu + ((x.u >> 16) & 1u);
    return (unsigned short)(r >> 16);
}

static __device__ __forceinline__ unsigned int pk2(float a, float b) {
    return (unsigned int)bf16r(a) | ((unsigned int)bf16r(b) << 16);
}

// ---------------------------------------------------------------------------
// Fused prep. grid (16,16,5) x 256 threads.
//  z<4 : V f32 -> Vt bf16 [B,H,hd,L] (per-head transpose via LDS).
//  z==4: W f32 -> Wbf bf16, 64x64 tile.
// ---------------------------------------------------------------------------
__global__ __launch_bounds__(256) void prep_kernel(
    const float* __restrict__ Vg, const float* __restrict__ Wg,
    unsigned short* __restrict__ Vtg, unsigned short* __restrict__ Wbf)
{
    const int tid = threadIdx.x;
    if (blockIdx.z == 4) {
        const int r0 = blockIdx.x * 64, c0 = blockIdx.y * 64;
#pragma unroll 4
        for (int i = 0; i < 4; ++i) {
            int e4 = i * 256 + tid;
            int r = e4 >> 4, c4 = e4 & 15;
            const float* p = Wg + (size_t)(r0 + r) * Dn + c0 + c4 * 4;
            float4 v = *(const float4*)p;
            ushort4 o;
            o.x = bf16r(v.x); o.y = bf16r(v.y); o.z = bf16r(v.z); o.w = bf16r(v.w);
            *(ushort4*)(Wbf + (size_t)(r0 + r) * Dn + c0 + c4 * 4) = o;
        }
        return;
    }

    __shared__ unsigned short T[64][72];   // [d][k]
    const int k0 = blockIdx.x * 64;
    const int h  = blockIdx.y;
    const int b  = blockIdx.z;
    const float* Vb = Vg + (size_t)b * Ln * Dn + h * HDn;

#pragma unroll 4
    for (int i = 0; i < 4; ++i) {
        int e4 = i * 256 + tid;
        int r = e4 >> 4, c4 = e4 & 15;
        float4 vv = *(const float4*)(Vb + (size_t)(k0 + r) * Dn + c4 * 4);
        T[c4 * 4 + 0][r] = bf16r(vv.x);
        T[c4 * 4 + 1][r] = bf16r(vv.y);
        T[c4 * 4 + 2][r] = bf16r(vv.z);
        T[c4 * 4 + 3][r] = bf16r(vv.w);
    }
    __syncthreads();
    unsigned short* out = Vtg + ((size_t)(b * Hn + h) * HDn) * Ln + k0;
#pragma unroll 2
    for (int i = 0; i < 2; ++i) {
        int e8 = i * 256 + tid;
        int r = e8 >> 3, c8 = e8 & 7;
        *(uint4*)(out + (size_t)r * Ln + c8 * 8) = *(const uint4*)&T[r][c8 * 8];
    }
}

// ---------------------------------------------------------------------------
// Flash attention, v9 = v8 (512 thr, q-tile 256, grid 256, single-barrier
// dbuf K staging w/ inline f32->bf16, XOR swizzle, builtin exp2, forced
// unrolls) MINUS the V LDS staging: V^T per (b,h) is 128 KB, L2-resident,
// and the 4 q-blocks of a (b,h) are XCD-colocated -> PV B-frags read
// DIRECTLY from global into regs (issued at tile top, T14 issue-early;
// latency hides under QK+exp). DS bytes/wave/tile 24.5->16.5 KB (-33%),
// the measured attn bottleneck. LDS 64->48 KB.
// ---------------------------------------------------------------------------
__global__ __launch_bounds__(512) void attn_kernel(
    const float* __restrict__ Qg, const float* __restrict__ Kg,
    const unsigned short* __restrict__ Vtg, unsigned short* __restrict__ Xg)
{
    __shared__ uint4 Ks4[2][64][8];    // 16 KB  (dbuf, swizzled cols)
    __shared__ uint2 Ps2[256][16];     // 32 KB  (swizzled, wave-private rows)

    const int tid  = threadIdx.x;
    const int wave = tid >> 6;     // 0..7
    const int lane = tid & 63;
    const int l16  = lane & 15;
    const int quad = lane >> 4;
    const int r7   = l16 & 7;      // swizzle key
    const int wb   = wave * 32;

    // XCD-aware decode: flat = xcd + 8*(qt + 4*gg); bh = xcd + 8*gg.
    const int flat = blockIdx.x;
    const int xcd  = flat & 7;
    const int j    = flat >> 3;
    const int qt   = j & 3;
    const int gg   = j >> 2;
    const int g    = xcd + 8 * gg;   // 0..63
    const int h    = g & 15;
    const int b    = g >> 4;
    const int q0   = qt * 256;

    const float* Kf = Kg + (size_t)b * Ln * Dn + h * HDn;                 // f32
    const unsigned short* Vtb16 = Vtg + ((size_t)(b * Hn + h) * HDn) * Ln; // bf16 [d][L]

    // Q fragments (read exactly once). B-operand layout: n=l16, k=quad*8+j.
    bf16x8 bq[2][2];
#pragma unroll 2
    for (int hf = 0; hf < 2; ++hf) {
        const float* qp = Qg + ((size_t)b * Ln + q0 + wb + hf * 16 + l16) * Dn
                             + h * HDn + quad * 8;
        float4 a0 = *(const float4*)qp;
        float4 a1 = *(const float4*)(qp + 4);
        float4 a2 = *(const float4*)(qp + 32);
        float4 a3 = *(const float4*)(qp + 36);
        bq[hf][0][0] = (short)bf16r(a0.x); bq[hf][0][1] = (short)bf16r(a0.y);
        bq[hf][0][2] = (short)bf16r(a0.z); bq[hf][0][3] = (short)bf16r(a0.w);
        bq[hf][0][4] = (short)bf16r(a1.x); bq[hf][0][5] = (short)bf16r(a1.y);
        bq[hf][0][6] = (short)bf16r(a1.z); bq[hf][0][7] = (short)bf16r(a1.w);
        bq[hf][1][0] = (short)bf16r(a2.x); bq[hf][1][1] = (short)bf16r(a2.y);
        bq[hf][1][2] = (short)bf16r(a2.z); bq[hf][1][3] = (short)bf16r(a2.w);
        bq[hf][1][4] = (short)bf16r(a3.x); bq[hf][1][5] = (short)bf16r(a3.y);
        bq[hf][1][6] = (short)bf16r(a3.z); bq[hf][1][7] = (short)bf16r(a3.w);
    }

    const float SC = 1.4426950408889634f / 32.0f;   // log2(e)/sqrt(D)

    float lsum[2] = {0.f, 0.f};
    f32x4 Oacc[2][4];
#pragma unroll 2
    for (int hf = 0; hf < 2; ++hf)
#pragma unroll 4
        for (int d = 0; d < 4; ++d) Oacc[hf][d] = (f32x4){0.f, 0.f, 0.f, 0.f};

    // K staging: 512 threads; 2 raw float4 (converted at the LDS-write point).
    const int sr = tid >> 3, sc = tid & 7;
    const int scs = sc ^ (sr & 7);           // swizzled column
    float4 kr0, kr1;

    // Prologue: tile 0 -> buf 0; issue tile-1 loads; one barrier.
    kr0 = *(const float4*)(Kf + (size_t)sr * Dn + sc * 8);
    kr1 = *(const float4*)(Kf + (size_t)sr * Dn + sc * 8 + 4);
    Ks4[0][sr][scs] = (uint4){pk2(kr0.x, kr0.y), pk2(kr0.z, kr0.w),
                              pk2(kr1.x, kr1.y), pk2(kr1.z, kr1.w)};
    kr0 = *(const float4*)(Kf + (size_t)(64 + sr) * Dn + sc * 8);
    kr1 = *(const float4*)(Kf + (size_t)(64 + sr) * Dn + sc * 8 + 4);
    __syncthreads();

    constexpr int NT = Ln / 64;
    for (int it = 0; it < NT; ++it) {
        const int cur = it & 1;
        const int k0 = it * 64;

        // V^T B-frags straight from global (L2-resident, XCD-local).
        // Issued BEFORE QK so ~200cy L2 latency hides under 16 MFMA + exp.
        bf16x8 vv[2][4];
#pragma unroll 2
        for (int kk = 0; kk < 2; ++kk)
#pragma unroll 4
            for (int dt = 0; dt < 4; ++dt)
                vv[kk][dt] = *(const bf16x8*)(Vtb16
                    + (size_t)(dt * 16 + l16) * Ln + k0 + kk * 32 + quad * 8);

        // S^T = K Q^T : A = K-frag (m=key), B = Q-frag (n=q). 8 reads, 16 MFMA.
        f32x4 st[2][4];
        __builtin_amdgcn_s_setprio(1);
#pragma unroll 4
        for (int n = 0; n < 4; ++n) {
            bf16x8 a0 = __builtin_bit_cast(bf16x8, Ks4[cur][n * 16 + l16][quad ^ r7]);
            bf16x8 a1 = __builtin_bit_cast(bf16x8, Ks4[cur][n * 16 + l16][(4 + quad) ^ r7]);
#pragma unroll 2
            for (int hf = 0; hf < 2; ++hf) {
                f32x4 acc = (f32x4){0.f, 0.f, 0.f, 0.f};
                acc = __builtin_amdgcn_mfma_f32_16x16x32_bf16(a0, bq[hf][0], acc, 0, 0, 0);
                acc = __builtin_amdgcn_mfma_f32_16x16x32_bf16(a1, bq[hf][1], acc, 0, 0, 0);
                st[hf][n] = acc;
            }
        }
        __builtin_amdgcn_s_setprio(0);

        // P = exp2(S^T * SC); packed b64 stores (swizzled); scalar row-sums.
#pragma unroll 2
        for (int hf = 0; hf < 2; ++hf) {
            float ls = 0.f;
#pragma unroll 4
            for (int n = 0; n < 4; ++n) {
                float p0 = __builtin_amdgcn_exp2f(st[hf][n][0] * SC);
                float p1 = __builtin_amdgcn_exp2f(st[hf][n][1] * SC);
                float p2 = __builtin_amdgcn_exp2f(st[hf][n][2] * SC);
                float p3 = __builtin_amdgcn_exp2f(st[hf][n][3] * SC);
                ls += (p0 + p1) + (p2 + p3);
                uint2 w;
                w.x = pk2(p0, p1);
                w.y = pk2(p2, p3);
                Ps2[wb + hf * 16 + l16][(n * 4 + quad) ^ (r7 << 1)] = w;
            }
            lsum[hf] += ls;
        }

        // O += P V. V frags already in regs; only ap comes from LDS.
        __builtin_amdgcn_s_setprio(1);
#pragma unroll 2
        for (int kk = 0; kk < 2; ++kk) {
#pragma unroll 2
            for (int hf = 0; hf < 2; ++hf) {
                int blk = (kk * 4 + quad) ^ r7;
                bf16x8 ap = *(const bf16x8*)&Ps2[wb + hf * 16 + l16][blk * 2];
#pragma unroll 4
                for (int dt = 0; dt < 4; ++dt)
                    Oacc[hf][dt] = __builtin_amdgcn_mfma_f32_16x16x32_bf16(
                        ap, vv[kk][dt], Oacc[hf][dt], 0, 0, 0);
            }
        }
        __builtin_amdgcn_s_setprio(0);

        // Stage K tile it+1 into the other buffer; issue loads for it+2.
        if (it + 1 < NT) {
            Ks4[cur ^ 1][sr][scs] = (uint4){pk2(kr0.x, kr0.y), pk2(kr0.z, kr0.w),
                                            pk2(kr1.x, kr1.y), pk2(kr1.z, kr1.w)};
            if (it + 2 < NT) {
                kr0 = *(const float4*)(Kf + (size_t)((it + 2) * 64 + sr) * Dn + sc * 8);
                kr1 = *(const float4*)(Kf + (size_t)((it + 2) * 64 + sr) * Dn + sc * 8 + 4);
            }
        }
        __syncthreads();
    }

    // Row sums live per-lane (q=l16); reduce across quads.
    float inv[2];
#pragma unroll 2
    for (int hf = 0; hf < 2; ++hf) {
        float rs = lsum[hf];
        rs += __shfl_xor(rs, 16, 64);
        rs += __shfl_xor(rs, 32, 64);
        inv[hf] = __builtin_amdgcn_rcpf(rs);
    }

    unsigned short* Xb = Xg + ((size_t)b * Ln + q0 + wb) * Dn + h * HDn;
#pragma unroll 2
    for (int hf = 0; hf < 2; ++hf)
#pragma unroll 4
        for (int r = 0; r < 4; ++r) {
            float iv = __shfl(inv[hf], quad * 4 + r, 64);
            int row = hf * 16 + quad * 4 + r;
#pragma unroll 4
            for (int dt = 0; dt < 4; ++dt)
                Xb[(size_t)row * Dn + dt * 16 + l16] = bf16r(Oacc[hf][dt][r] * iv);
        }
}

// ---------------------------------------------------------------------------
// Projection: Y = X @ W^T + b.  (unchanged)
// ---------------------------------------------------------------------------
__global__ __launch_bounds__(256) void proj_kernel(
    const unsigned short* __restrict__ Xg, const unsigned short* __restrict__ Wbf,
    const float* __restrict__ bg, float* __restrict__ Yg)
{
    __shared__ unsigned short XsL[128 * 64];   // 16 KB, linear (no pad!)
    __shared__ unsigned short WsL[64 * 64];    // 8 KB, linear

    const int tid  = threadIdx.x;
    const int wave = tid >> 6;
    const int lane = tid & 63;
    const int l16  = lane & 15;
    const int quad = lane >> 4;
    const int mw   = (wave & 1) * 64;
    const int nw   = (wave >> 1) * 32;

    const int m0 = blockIdx.x * 128;
    const int n0 = blockIdx.y * 64;

    f32x4 acc[4][2];
#pragma unroll 4
    for (int mt = 0; mt < 4; ++mt)
#pragma unroll 2
        for (int nt = 0; nt < 2; ++nt)
            acc[mt][nt] = (f32x4){0.f, 0.f, 0.f, 0.f};

    for (int it = 0; it < Dn / 64; ++it) {
        const int kk0 = it * 64;
        __syncthreads();   // previous iteration's reads done
#pragma unroll 4
        for (int i = 0; i < 4; ++i) {
            int fl = i * 256 + tid;            // 1024 x 16B = 16 KB (X tile)
            int r = fl >> 3, c8 = fl & 7;
            __builtin_amdgcn_global_load_lds(
                (const __attribute__((address_space(1))) void*)
                    (Xg + (size_t)(m0 + r) * Dn + kk0 + c8 * 8),
                (__attribute__((address_space(3))) void*)&XsL[fl * 8],
                16, 0, 0);
        }
#pragma unroll 2
        for (int i = 0; i < 2; ++i) {
            int fl = i * 256 + tid;            // 512 x 16B = 8 KB (W tile)
            int r = fl >> 3, c8 = fl & 7;
            __builtin_amdgcn_global_load_lds(
                (const __attribute__((address_space(1))) void*)
                    (Wbf + (size_t)(n0 + r) * Dn + kk0 + c8 * 8),
                (__attribute__((address_space(3))) void*)&WsL[fl * 8],
                16, 0, 0);
        }
        __syncthreads();   // vmcnt(0) drain: tile resident

        __builtin_amdgcn_s_setprio(1);
#pragma unroll 2
        for (int ks = 0; ks < 2; ++ks) {
            bf16x8 af[4], bfr[2];
#pragma unroll 4
            for (int mt = 0; mt < 4; ++mt)
                af[mt] = *(const bf16x8*)&XsL[(mw + mt * 16 + l16) * 64 + ks * 32 + quad * 8];
#pragma unroll 2
            for (int nt = 0; nt < 2; ++nt)
                bfr[nt] = *(const bf16x8*)&WsL[(nw + nt * 16 + l16) * 64 + ks * 32 + quad * 8];
#pragma unroll 4
            for (int mt = 0; mt < 4; ++mt)
#pragma unroll 2
                for (int nt = 0; nt < 2; ++nt)
                    acc[mt][nt] = __builtin_amdgcn_mfma_f32_16x16x32_bf16(
                        af[mt], bfr[nt], acc[mt][nt], 0, 0, 0);
        }
        __builtin_amdgcn_s_setprio(0);
    }

#pragma unroll 2
    for (int nt = 0; nt < 2; ++nt) {
        int col = n0 + nw + nt * 16 + l16;
        float bb = bg[col];
#pragma unroll 4
        for (int mt = 0; mt < 4; ++mt)
#pragma unroll 4
            for (int r = 0; r < 4; ++r) {
                int row = m0 + mw + mt * 16 + quad * 4 + r;
                Yg[(size_t)row * Dn + col] = acc[mt][nt][r] + bb;
            }
    }
}

extern "C" void kernel_launch(void* const* d_in, const int* in_sizes, int n_in,
                              void* d_out, int out_size, void* d_ws, size_t ws_size,
                              hipStream_t stream) {
    const float* Q    = (const float*)d_in[0];
    const float* K    = (const float*)d_in[1];
    const float* V    = (const float*)d_in[2];
    const float* W    = (const float*)d_in[3];
    const float* bias = (const float*)d_in[4];

    unsigned short* Vt  = (unsigned short*)d_ws;                  // 8 MB
    unsigned short* Wbf = Vt + (size_t)Bn * Ln * Dn;              // 2 MB
    unsigned short* X   = Wbf + (size_t)Dn * Dn;                  // 8 MB
    float* Y = (float*)d_out;

    dim3 gp(Ln / 64, Hn, Bn + 1);        // z=0..3: V prep; z=4: W prep
    prep_kernel<<<gp, 256, 0, stream>>>(V, W, Vt, Wbf);

    attn_kernel<<<dim3(256, 1, 1), 512, 0, stream>>>(Q, K, Vt, X);

    dim3 g2(Bn * Ln / 128, Dn / 64);     // 32 x 16 = 512 blocks, 2/CU
    proj_kernel<<<g2, 256, 0, stream>>>(X, Wbf, bias, Y);
}

// Round 11
// 144.376 us; speedup vs baseline: 1.0817x; 1.0817x over previous
//
#include <hip/hip_runtime.h>
#include <hip/hip_bf16.h>

typedef __attribute__((ext_vector_type(4))) float f32x4;
typedef __attribute__((ext_vector_type(8))) short bf16x8;

constexpr int Bn  = 4;
constexpr int Ln  = 1024;
constexpr int Dn  = 1024;
constexpr int Hn  = 16;
constexpr int HDn = 64;

static __device__ __forceinline__ unsigned short bf16r(float f) {
    union { float f; unsigned int u; } x;
    x.f = f;
    unsigned int r = x.u + 0x7fffu + ((x.u >> 16) & 1u);
    return (unsigned short)(r >> 16);
}

static __device__ __forceinline__ unsigned int pk2(float a, float b) {
    return (unsigned int)bf16r(a) | ((unsigned int)bf16r(b) << 16);
}

// ---------------------------------------------------------------------------
// Fused prep. grid (16,16,5) x 256 threads.
//  z<4 : V f32 -> Vt bf16 [B,H,hd,L] (per-head transpose via LDS).
//  z==4: W f32 -> Wbf bf16, 64x64 tile.
// ---------------------------------------------------------------------------
__global__ __launch_bounds__(256) void prep_kernel(
    const float* __restrict__ Vg, const float* __restrict__ Wg,
    unsigned short* __restrict__ Vtg, unsigned short* __restrict__ Wbf)
{
    const int tid = threadIdx.x;
    if (blockIdx.z == 4) {
        const int r0 = blockIdx.x * 64, c0 = blockIdx.y * 64;
#pragma unroll 4
        for (int i = 0; i < 4; ++i) {
            int e4 = i * 256 + tid;
            int r = e4 >> 4, c4 = e4 & 15;
            const float* p = Wg + (size_t)(r0 + r) * Dn + c0 + c4 * 4;
            float4 v = *(const float4*)p;
            ushort4 o;
            o.x = bf16r(v.x); o.y = bf16r(v.y); o.z = bf16r(v.z); o.w = bf16r(v.w);
            *(ushort4*)(Wbf + (size_t)(r0 + r) * Dn + c0 + c4 * 4) = o;
        }
        return;
    }

    __shared__ unsigned short T[64][72];   // [d][k]
    const int k0 = blockIdx.x * 64;
    const int h  = blockIdx.y;
    const int b  = blockIdx.z;
    const float* Vb = Vg + (size_t)b * Ln * Dn + h * HDn;

#pragma unroll 4
    for (int i = 0; i < 4; ++i) {
        int e4 = i * 256 + tid;
        int r = e4 >> 4, c4 = e4 & 15;
        float4 vv = *(const float4*)(Vb + (size_t)(k0 + r) * Dn + c4 * 4);
        T[c4 * 4 + 0][r] = bf16r(vv.x);
        T[c4 * 4 + 1][r] = bf16r(vv.y);
        T[c4 * 4 + 2][r] = bf16r(vv.z);
        T[c4 * 4 + 3][r] = bf16r(vv.w);
    }
    __syncthreads();
    unsigned short* out = Vtg + ((size_t)(b * Hn + h) * HDn) * Ln + k0;
#pragma unroll 2
    for (int i = 0; i < 2; ++i) {
        int e8 = i * 256 + tid;
        int r = e8 >> 3, c8 = e8 & 7;
        *(uint4*)(out + (size_t)r * Ln + c8 * 8) = *(const uint4*)&T[r][c8 * 8];
    }
}

// ---------------------------------------------------------------------------
// Flash attention = round-9 v8 (best measured: 512 thr, q-tile 256, grid 256,
// single-barrier dbuf K staging w/ inline f32->bf16, V staged in LDS, XOR
// swizzle, builtin exp2, forced unrolls). Round-10's V-from-global variant
// regressed (vmcnt serialization) -> reverted.
// ---------------------------------------------------------------------------
__global__ __launch_bounds__(512) void attn_kernel(
    const float* __restrict__ Qg, const float* __restrict__ Kg,
    const unsigned short* __restrict__ Vtg, unsigned short* __restrict__ Xg)
{
    __shared__ uint4 Ks4[2][64][8];    // 16 KB  (dbuf, swizzled cols)
    __shared__ uint4 Vts4[2][64][8];   // 16 KB  [d][k]
    __shared__ uint2 Ps2[256][16];     // 32 KB  (swizzled, wave-private rows)

    const int tid  = threadIdx.x;
    const int wave = tid >> 6;     // 0..7
    const int lane = tid & 63;
    const int l16  = lane & 15;
    const int quad = lane >> 4;
    const int r7   = l16 & 7;      // swizzle key
    const int wb   = wave * 32;

    // XCD-aware decode: flat = xcd + 8*(qt + 4*gg); bh = xcd + 8*gg.
    const int flat = blockIdx.x;
    const int xcd  = flat & 7;
    const int j    = flat >> 3;
    const int qt   = j & 3;
    const int gg   = j >> 2;
    const int g    = xcd + 8 * gg;   // 0..63
    const int h    = g & 15;
    const int b    = g >> 4;
    const int q0   = qt * 256;

    const float* Kf   = Kg + (size_t)b * Ln * Dn + h * HDn;               // f32
    const uint4* Vtb4 = (const uint4*)(Vtg + ((size_t)(b * Hn + h) * HDn) * Ln);

    // Q fragments (read exactly once). B-operand layout: n=l16, k=quad*8+j.
    bf16x8 bq[2][2];
#pragma unroll 2
    for (int hf = 0; hf < 2; ++hf) {
        const float* qp = Qg + ((size_t)b * Ln + q0 + wb + hf * 16 + l16) * Dn
                             + h * HDn + quad * 8;
        float4 a0 = *(const float4*)qp;
        float4 a1 = *(const float4*)(qp + 4);
        float4 a2 = *(const float4*)(qp + 32);
        float4 a3 = *(const float4*)(qp + 36);
        bq[hf][0][0] = (short)bf16r(a0.x); bq[hf][0][1] = (short)bf16r(a0.y);
        bq[hf][0][2] = (short)bf16r(a0.z); bq[hf][0][3] = (short)bf16r(a0.w);
        bq[hf][0][4] = (short)bf16r(a1.x); bq[hf][0][5] = (short)bf16r(a1.y);
        bq[hf][0][6] = (short)bf16r(a1.z); bq[hf][0][7] = (short)bf16r(a1.w);
        bq[hf][1][0] = (short)bf16r(a2.x); bq[hf][1][1] = (short)bf16r(a2.y);
        bq[hf][1][2] = (short)bf16r(a2.z); bq[hf][1][3] = (short)bf16r(a2.w);
        bq[hf][1][4] = (short)bf16r(a3.x); bq[hf][1][5] = (short)bf16r(a3.y);
        bq[hf][1][6] = (short)bf16r(a3.z); bq[hf][1][7] = (short)bf16r(a3.w);
    }

    const float SC = 1.4426950408889634f / 32.0f;   // log2(e)/sqrt(D)

    float lsum[2] = {0.f, 0.f};
    f32x4 Oacc[2][4];
#pragma unroll 2
    for (int hf = 0; hf < 2; ++hf)
#pragma unroll 4
        for (int d = 0; d < 4; ++d) Oacc[hf][d] = (f32x4){0.f, 0.f, 0.f, 0.f};

    // Staging: 512 threads; K = 2 raw float4 (converted at write), V = uint4.
    const int sr = tid >> 3, sc = tid & 7;
    const int scs = sc ^ (sr & 7);           // swizzled column
    float4 kr0, kr1;
    uint4 vreg;

    // Prologue: tile 0 -> buf 0; issue tile-1 loads; one barrier.
    kr0 = *(const float4*)(Kf + (size_t)sr * Dn + sc * 8);
    kr1 = *(const float4*)(Kf + (size_t)sr * Dn + sc * 8 + 4);
    vreg = Vtb4[(size_t)sr * 128 + sc];
    Ks4[0][sr][scs] = (uint4){pk2(kr0.x, kr0.y), pk2(kr0.z, kr0.w),
                              pk2(kr1.x, kr1.y), pk2(kr1.z, kr1.w)};
    Vts4[0][sr][scs] = vreg;
    kr0 = *(const float4*)(Kf + (size_t)(64 + sr) * Dn + sc * 8);
    kr1 = *(const float4*)(Kf + (size_t)(64 + sr) * Dn + sc * 8 + 4);
    vreg = Vtb4[(size_t)sr * 128 + 8 + sc];
    __syncthreads();

    constexpr int NT = Ln / 64;
    for (int it = 0; it < NT; ++it) {
        const int cur = it & 1;

        // S^T = K Q^T : A = K-frag (m=key), B = Q-frag (n=q). 8 reads, 16 MFMA.
        f32x4 st[2][4];
        __builtin_amdgcn_s_setprio(1);
#pragma unroll 4
        for (int n = 0; n < 4; ++n) {
            bf16x8 a0 = __builtin_bit_cast(bf16x8, Ks4[cur][n * 16 + l16][quad ^ r7]);
            bf16x8 a1 = __builtin_bit_cast(bf16x8, Ks4[cur][n * 16 + l16][(4 + quad) ^ r7]);
#pragma unroll 2
            for (int hf = 0; hf < 2; ++hf) {
                f32x4 acc = (f32x4){0.f, 0.f, 0.f, 0.f};
                acc = __builtin_amdgcn_mfma_f32_16x16x32_bf16(a0, bq[hf][0], acc, 0, 0, 0);
                acc = __builtin_amdgcn_mfma_f32_16x16x32_bf16(a1, bq[hf][1], acc, 0, 0, 0);
                st[hf][n] = acc;
            }
        }
        __builtin_amdgcn_s_setprio(0);

        // P = exp2(S^T * SC); packed b64 stores (swizzled); scalar row-sums.
#pragma unroll 2
        for (int hf = 0; hf < 2; ++hf) {
            float ls = 0.f;
#pragma unroll 4
            for (int n = 0; n < 4; ++n) {
                float p0 = __builtin_amdgcn_exp2f(st[hf][n][0] * SC);
                float p1 = __builtin_amdgcn_exp2f(st[hf][n][1] * SC);
                float p2 = __builtin_amdgcn_exp2f(st[hf][n][2] * SC);
                float p3 = __builtin_amdgcn_exp2f(st[hf][n][3] * SC);
                ls += (p0 + p1) + (p2 + p3);
                uint2 w;
                w.x = pk2(p0, p1);
                w.y = pk2(p2, p3);
                Ps2[wb + hf * 16 + l16][(n * 4 + quad) ^ (r7 << 1)] = w;
            }
            lsum[hf] += ls;
        }

        // O += P V. V B-frags shared across the two q-halves.
        __builtin_amdgcn_s_setprio(1);
#pragma unroll 2
        for (int kk = 0; kk < 2; ++kk) {
            bf16x8 bv[4];
#pragma unroll 4
            for (int dt = 0; dt < 4; ++dt)
                bv[dt] = __builtin_bit_cast(bf16x8,
                    Vts4[cur][dt * 16 + l16][(kk * 4 + quad) ^ r7]);
#pragma unroll 2
            for (int hf = 0; hf < 2; ++hf) {
                int blk = (kk * 4 + quad) ^ r7;
                bf16x8 ap = *(const bf16x8*)&Ps2[wb + hf * 16 + l16][blk * 2];
#pragma unroll 4
                for (int dt = 0; dt < 4; ++dt)
                    Oacc[hf][dt] = __builtin_amdgcn_mfma_f32_16x16x32_bf16(
                        ap, bv[dt], Oacc[hf][dt], 0, 0, 0);
            }
        }
        __builtin_amdgcn_s_setprio(0);

        // Stage tile it+1 into the other buffer (overlaps other waves'
        // compute); issue loads for tile it+2. ONE barrier per tile.
        if (it + 1 < NT) {
            Ks4[cur ^ 1][sr][scs] = (uint4){pk2(kr0.x, kr0.y), pk2(kr0.z, kr0.w),
                                            pk2(kr1.x, kr1.y), pk2(kr1.z, kr1.w)};
            Vts4[cur ^ 1][sr][scs] = vreg;
            if (it + 2 < NT) {
                kr0 = *(const float4*)(Kf + (size_t)((it + 2) * 64 + sr) * Dn + sc * 8);
                kr1 = *(const float4*)(Kf + (size_t)((it + 2) * 64 + sr) * Dn + sc * 8 + 4);
                vreg = Vtb4[(size_t)sr * 128 + (it + 2) * 8 + sc];
            }
        }
        __syncthreads();
    }

    // Row sums live per-lane (q=l16); reduce across quads.
    float inv[2];
#pragma unroll 2
    for (int hf = 0; hf < 2; ++hf) {
        float rs = lsum[hf];
        rs += __shfl_xor(rs, 16, 64);
        rs += __shfl_xor(rs, 32, 64);
        inv[hf] = __builtin_amdgcn_rcpf(rs);
    }

    unsigned short* Xb = Xg + ((size_t)b * Ln + q0 + wb) * Dn + h * HDn;
#pragma unroll 2
    for (int hf = 0; hf < 2; ++hf)
#pragma unroll 4
        for (int r = 0; r < 4; ++r) {
            float iv = __shfl(inv[hf], quad * 4 + r, 64);
            int row = hf * 16 + quad * 4 + r;
#pragma unroll 4
            for (int dt = 0; dt < 4; ++dt)
                Xb[(size_t)row * Dn + dt * 16 + l16] = bf16r(Oacc[hf][dt][r] * iv);
        }
}

// ---------------------------------------------------------------------------
// Projection v3: Y = X @ W^T + b.  2-PHASE double-buffered (T3 minimum):
// per iter {issue STAGE(t+1) -> compute(t) -> barrier}. __syncthreads drains
// vmcnt, so the stage issued this iter is resident next iter; the load
// latency hides under this iter's ds_read+MFMA. 64x64 tile, BK=64, dbuf LDS
// 32 KB (multi-block/CU residency). Grid 64x16 = 1024 blocks. 4 waves,
// 32x32 quadrant each.
// ---------------------------------------------------------------------------
__global__ __launch_bounds__(256) void proj_kernel(
    const unsigned short* __restrict__ Xg, const unsigned short* __restrict__ Wbf,
    const float* __restrict__ bg, float* __restrict__ Yg)
{
    __shared__ unsigned short XsL[2][64 * 64];   // 2 x 8 KB
    __shared__ unsigned short WsL[2][64 * 64];   // 2 x 8 KB

    const int tid  = threadIdx.x;
    const int wave = tid >> 6;
    const int lane = tid & 63;
    const int l16  = lane & 15;
    const int quad = lane >> 4;
    const int mw   = (wave & 1) * 32;
    const int nw   = (wave >> 1) * 32;

    const int m0 = blockIdx.x * 64;
    const int n0 = blockIdx.y * 64;

    f32x4 acc[2][2];
#pragma unroll 2
    for (int mt = 0; mt < 2; ++mt)
#pragma unroll 2
        for (int nt = 0; nt < 2; ++nt)
            acc[mt][nt] = (f32x4){0.f, 0.f, 0.f, 0.f};

    // Prologue: stage tile 0 into buf 0; barrier drains it.
#pragma unroll 2
    for (int i = 0; i < 2; ++i) {
        int fl = i * 256 + tid;            // 512 x 16B = 8 KB each
        int r = fl >> 3, c8 = fl & 7;
        __builtin_amdgcn_global_load_lds(
            (const __attribute__((address_space(1))) void*)
                (Xg + (size_t)(m0 + r) * Dn + c8 * 8),
            (__attribute__((address_space(3))) void*)&XsL[0][fl * 8], 16, 0, 0);
        __builtin_amdgcn_global_load_lds(
            (const __attribute__((address_space(1))) void*)
                (Wbf + (size_t)(n0 + r) * Dn + c8 * 8),
            (__attribute__((address_space(3))) void*)&WsL[0][fl * 8], 16, 0, 0);
    }
    __syncthreads();

    constexpr int NI = Dn / 64;   // 16
    for (int it = 0; it < NI; ++it) {
        const int cur = it & 1;

        // Issue next tile's stage into the other buffer (async, overlaps
        // this iteration's compute; drained by the barrier below).
        if (it + 1 < NI) {
            const int kk1 = (it + 1) * 64;
#pragma unroll 2
            for (int i = 0; i < 2; ++i) {
                int fl = i * 256 + tid;
                int r = fl >> 3, c8 = fl & 7;
                __builtin_amdgcn_global_load_lds(
                    (const __attribute__((address_space(1))) void*)
                        (Xg + (size_t)(m0 + r) * Dn + kk1 + c8 * 8),
                    (__attribute__((address_space(3))) void*)&XsL[cur ^ 1][fl * 8],
                    16, 0, 0);
                __builtin_amdgcn_global_load_lds(
                    (const __attribute__((address_space(1))) void*)
                        (Wbf + (size_t)(n0 + r) * Dn + kk1 + c8 * 8),
                    (__attribute__((address_space(3))) void*)&WsL[cur ^ 1][fl * 8],
                    16, 0, 0);
            }
        }

        __builtin_amdgcn_s_setprio(1);
#pragma unroll 2
        for (int ks = 0; ks < 2; ++ks) {
            bf16x8 af[2], bfr[2];
#pragma unroll 2
            for (int mt = 0; mt < 2; ++mt)
                af[mt] = *(const bf16x8*)&XsL[cur][(mw + mt * 16 + l16) * 64
                                                  + ks * 32 + quad * 8];
#pragma unroll 2
            for (int nt = 0; nt < 2; ++nt)
                bfr[nt] = *(const bf16x8*)&WsL[cur][(nw + nt * 16 + l16) * 64
                                                   + ks * 32 + quad * 8];
#pragma unroll 2
            for (int mt = 0; mt < 2; ++mt)
#pragma unroll 2
                for (int nt = 0; nt < 2; ++nt)
                    acc[mt][nt] = __builtin_amdgcn_mfma_f32_16x16x32_bf16(
                        af[mt], bfr[nt], acc[mt][nt], 0, 0, 0);
        }
        __builtin_amdgcn_s_setprio(0);

        __syncthreads();   // drains vmcnt (next tile resident) + reads done
    }

#pragma unroll 2
    for (int nt = 0; nt < 2; ++nt) {
        int col = n0 + nw + nt * 16 + l16;
        float bb = bg[col];
#pragma unroll 2
        for (int mt = 0; mt < 2; ++mt)
#pragma unroll 4
            for (int r = 0; r < 4; ++r) {
                int row = m0 + mw + mt * 16 + quad * 4 + r;
                Yg[(size_t)row * Dn + col] = acc[mt][nt][r] + bb;
            }
    }
}

extern "C" void kernel_launch(void* const* d_in, const int* in_sizes, int n_in,
                              void* d_out, int out_size, void* d_ws, size_t ws_size,
                              hipStream_t stream) {
    const float* Q    = (const float*)d_in[0];
    const float* K    = (const float*)d_in[1];
    const float* V    = (const float*)d_in[2];
    const float* W    = (const float*)d_in[3];
    const float* bias = (const float*)d_in[4];

    unsigned short* Vt  = (unsigned short*)d_ws;                  // 8 MB
    unsigned short* Wbf = Vt + (size_t)Bn * Ln * Dn;              // 2 MB
    unsigned short* X   = Wbf + (size_t)Dn * Dn;                  // 8 MB
    float* Y = (float*)d_out;

    dim3 gp(Ln / 64, Hn, Bn + 1);        // z=0..3: V prep; z=4: W prep
    prep_kernel<<<gp, 256, 0, stream>>>(V, W, Vt, Wbf);

    attn_kernel<<<dim3(256, 1, 1), 512, 0, stream>>>(Q, K, Vt, X);

    dim3 g2(Bn * Ln / 64, Dn / 64);      // 64 x 16 = 1024 blocks
    proj_kernel<<<g2, 256, 0, stream>>>(X, Wbf, bias, Y);
}